// Round 5
// baseline (124.181 us; speedup 1.0000x reference)
//
#include <hip/hip_runtime.h>
#include <stdint.h>

#define S 4
#define B 64
#define D 32
#define N 784
#define P 2
#define L 10
#define HALF 392
#define NSTEP 391
#define NPAIR 196              // 195 real pairs + 1 leftover single site
#define SLICE 4096             // floats per pair slice: 4 combos * 32*32

typedef float f4 __attribute__((ext_vector_type(4)));

__device__ __forceinline__ float bcast(float v, int lane) {
    return __uint_as_float(__builtin_amdgcn_readlane(__float_as_uint(v), lane));
}

// ---------------- precompute: pair matrices + weight table ----------------
// W layout (per stream,t): float4-chunk index (bb*8+qq)*64 + lane, lane = c2*32+f,
// chunk holds content[c = c2+2*bb][f][e = 4*qq + r], r = component.
// left:  content[c][f][e] = P_c[e][f];  right: content[c][f][e] = Q_c[f][e].
__global__ __launch_bounds__(256) void pair_kernel(
    const float* __restrict__ A_left, const float* __restrict__ A_right,
    const float* __restrict__ x,
    float* __restrict__ Wbuf, float* __restrict__ wtab)
{
    const int stream = blockIdx.x;      // 0..7 -> linear_id % 8 == stream (XCD pin)
    const int t      = blockIdx.y;      // 0..195
    const int side   = stream >> 2, s = stream & 3;
    __shared__ float sA[2048], sB[2048];
    const int tid = threadIdx.x;
    const bool leftover = (t == 195);

    const float* As = (side ? A_right : A_left) + (size_t)s * (NSTEP * 2048);
    int ia, ib;
    if (side == 0) { ia = 2 * t; ib = 2 * t + 1; }
    else           { ia = 389 - 2 * t; ib = 390 - 2 * t; }
    if (leftover)  { ia = side ? 0 : 390; ib = ia; }

    const float4* ga = (const float4*)(As + (size_t)ia * 2048);
    const float4* gb = (const float4*)(As + (size_t)ib * 2048);
    ((float4*)sA)[tid] = ga[tid]; ((float4*)sA)[tid + 256] = ga[tid + 256];
    ((float4*)sB)[tid] = gb[tid]; ((float4*)sB)[tid + 256] = gb[tid + 256];
    __syncthreads();

    const int c = tid >> 6, rest = tid & 63, ff = rest >> 1, eh = rest & 1;
    const int a = c & 1, bb = c >> 1;
    float out[16];

    if (!leftover) {
        if (side == 0) {
            float col[32];
            #pragma unroll
            for (int k = 0; k < 32; ++k) col[k] = sB[k * 64 + bb * 32 + ff];
            #pragma unroll
            for (int e0 = 0; e0 < 16; ++e0) {
                const int e = eh * 16 + e0; float acc = 0.f;
                #pragma unroll
                for (int k = 0; k < 32; ++k)
                    acc = fmaf(sA[e * 64 + a * 32 + k], col[k], acc);
                out[e0] = acc;
            }
        } else {
            float row[32];
            #pragma unroll
            for (int k = 0; k < 32; ++k) row[k] = sA[ff * 64 + a * 32 + k];
            #pragma unroll
            for (int e0 = 0; e0 < 16; ++e0) {
                const int e = eh * 16 + e0; float acc = 0.f;
                #pragma unroll
                for (int k = 0; k < 32; ++k)
                    acc = fmaf(row[k], sB[k * 64 + bb * 32 + e], acc);
                out[e0] = acc;
            }
        }
    } else {
        #pragma unroll
        for (int e0 = 0; e0 < 16; ++e0) {
            const int e = eh * 16 + e0;
            out[e0] = (side == 0) ? sA[e * 64 + a * 32 + ff]
                                  : sA[ff * 64 + a * 32 + e];
        }
    }

    float* Wt = Wbuf + ((size_t)stream * NPAIR + t) * SLICE;
    #pragma unroll
    for (int q0 = 0; q0 < 4; ++q0) {
        const int qq = eh * 4 + q0;
        float4 val = make_float4(out[q0 * 4 + 0], out[q0 * 4 + 1],
                                 out[q0 * 4 + 2], out[q0 * 4 + 3]);
        ((float4*)Wt)[(bb * 8 + qq) * 64 + a * 32 + ff] = val;
    }

    // fused weight table: w[c=a+2b] = xa[a]*xb[b] for (side = stream, t, b = tid)
    if (stream < 2 && tid < 64) {
        const int sd = stream;
        const float2* x2 = (const float2*)x;
        float2 xa, xb;
        if (!leftover) {
            int na, nb;
            if (sd == 0) { na = 2 * t + 1; nb = 2 * t + 2; }
            else         { int ma = 389 - 2 * t; na = HALF + ma; nb = na + 1; }
            xa = x2[(size_t)tid * N + na];
            xb = x2[(size_t)tid * N + nb];
        } else {
            xa = x2[(size_t)tid * N + (sd ? HALF : 391)];
            xb = make_float2(1.f, 0.f);
        }
        float4 w = make_float4(xa.x * xb.x, xa.y * xb.x, xa.x * xb.y, xa.y * xb.y);
        ((float4*)wtab)[((size_t)sd * NPAIR + t) * 64 + tid] = w;
    }
}

// ---------------- chain kernel: register-ring pipeline, 2 chains/wave ----------------
#define GLOAD4(dst, ptr, off) \
    asm volatile("global_load_dwordx4 %0, %1, off offset:" #off \
                 : "=v"(dst) : "v"(ptr))

#define ISSUE_SLOT(SL) do { \
    GLOAD4(SL##0,  pA, 0); GLOAD4(SL##1,  pA, 1024); GLOAD4(SL##2,  pA, 2048); GLOAD4(SL##3,  pA, 3072); \
    GLOAD4(SL##4,  pB, 0); GLOAD4(SL##5,  pB, 1024); GLOAD4(SL##6,  pB, 2048); GLOAD4(SL##7,  pB, 3072); \
    GLOAD4(SL##8,  pC, 0); GLOAD4(SL##9,  pC, 1024); GLOAD4(SL##10, pC, 2048); GLOAD4(SL##11, pC, 3072); \
    GLOAD4(SL##12, pD, 0); GLOAD4(SL##13, pD, 1024); GLOAD4(SL##14, pD, 2048); GLOAD4(SL##15, pD, 3072); \
    GLOAD4(SL##w0, pw, 0); GLOAD4(SL##w1, pw, 16); \
    pA += SLICE; pB += SLICE; pC += SLICE; pD += SLICE; pw += 256; \
} while (0)

#define WAIT(n) do { \
    asm volatile("s_waitcnt vmcnt(" #n ")"); \
    __builtin_amdgcn_sched_barrier(0); \
} while (0)

// One e-quad: RqL = combo c2 chunk, RqH = combo c2+2 chunk; explicit readlane CSE.
#define FMAD2_1(RL_, RH_, aL0, aH0, aL1, aH1, E) do { \
    const float s_ = bcast(v0, E), t_ = bcast(v1, E); \
    aL0 = fmaf(RL_, s_, aL0); aH0 = fmaf(RH_, s_, aH0); \
    aL1 = fmaf(RL_, t_, aL1); aH1 = fmaf(RH_, t_, aH1); \
} while (0)

#define FMAD2(RqL, RqH, aL0, aH0, aL1, aH1, eb) \
    FMAD2_1(RqL.x, RqH.x, aL0, aH0, aL1, aH1, eb + 0); \
    FMAD2_1(RqL.y, RqH.y, aL0, aH0, aL1, aH1, eb + 1); \
    FMAD2_1(RqL.z, RqH.z, aL0, aH0, aL1, aH1, eb + 2); \
    FMAD2_1(RqL.w, RqH.w, aL0, aH0, aL1, aH1, eb + 3);

#define CONSUME_SLOT(SL) do { \
    float q00 = 0.f, q01 = 0.f, q02 = 0.f, q03 = 0.f; \
    float q10 = 0.f, q11 = 0.f, q12 = 0.f, q13 = 0.f; \
    FMAD2(SL##0, SL##8,  q00, q02, q10, q12, 0)  \
    FMAD2(SL##1, SL##9,  q00, q02, q10, q12, 4)  \
    FMAD2(SL##2, SL##10, q00, q02, q10, q12, 8)  \
    FMAD2(SL##3, SL##11, q00, q02, q10, q12, 12) \
    FMAD2(SL##4, SL##12, q01, q03, q11, q13, 16) \
    FMAD2(SL##5, SL##13, q01, q03, q11, q13, 20) \
    FMAD2(SL##6, SL##14, q01, q03, q11, q13, 24) \
    FMAD2(SL##7, SL##15, q01, q03, q11, q13, 28) \
    const float wl0 = c2 ? SL##w0.y : SL##w0.x, wh0 = c2 ? SL##w0.w : SL##w0.z; \
    const float wl1 = c2 ? SL##w1.y : SL##w1.x, wh1 = c2 ? SL##w1.w : SL##w1.z; \
    const float part0 = fmaf(wl0, q00 + q01, wh0 * (q02 + q03)); \
    const float part1 = fmaf(wl1, q10 + q11, wh1 * (q12 + q13)); \
    v0 = part0 + __shfl_xor(part0, 32); \
    v1 = part1 + __shfl_xor(part1, 32); \
} while (0)

// 256 blocks x 64 threads: 1 wave = 2 chains (b0,b1) of one stream. No barriers.
// blk&7 = stream (XCD-pinned). lane = (c2, f).
__global__ __launch_bounds__(64, 1) void chain_kernel(
    const float* __restrict__ x,
    const float* __restrict__ A_first, const float* __restrict__ A_last,
    const float* __restrict__ Wbuf, const float* __restrict__ wtab,
    float* __restrict__ ws_v)
{
    const int lane = threadIdx.x, c2 = lane >> 5, f = lane & 31;
    const int blk = blockIdx.x, stream = blk & 7;
    const int side = stream >> 2, s = stream & 3;
    const int bp = blk >> 3;              // 0..31
    const int b0 = 2 * bp, b1 = 2 * bp + 1;

    const float2* x2 = (const float2*)x;
    const int site0 = side ? (N - 1) : 0;
    const float2 af  = ((const float2*)(side ? A_last : A_first))[s * D + f];
    const float2 xx0 = x2[(size_t)b0 * N + site0];
    const float2 xx1 = x2[(size_t)b1 * N + site0];
    float v0 = fmaf(af.x, xx0.x, af.y * xx0.y);
    float v1 = fmaf(af.x, xx1.x, af.y * xx1.y);

    const float* Wstream = Wbuf + (size_t)stream * (NPAIR * SLICE);
    const float* pA = Wstream + (size_t)lane * 4;
    const float* pB = pA + 1024;
    const float* pC = pA + 2048;
    const float* pD = pA + 3072;
    const float* pw = wtab + (((size_t)side * NPAIR) * 64 + 2 * bp) * 4;

    f4 A0,A1,A2,A3,A4,A5,A6,A7,A8,A9,A10,A11,A12,A13,A14,A15,Aw0,Aw1;
    f4 B0,B1,B2,B3,B4,B5,B6,B7,B8,B9,B10,B11,B12,B13,B14,B15,Bw0,Bw1;
    f4 C0,C1,C2,C3,C4,C5,C6,C7,C8,C9,C10,C11,C12,C13,C14,C15,Cw0,Cw1;

    ISSUE_SLOT(A);   // t = 0
    ISSUE_SLOT(B);   // t = 1

    for (int k = 0; k < 64; ++k) {   // consumes t = 0..191
        ISSUE_SLOT(C); WAIT(36); CONSUME_SLOT(A);
        ISSUE_SLOT(A); WAIT(36); CONSUME_SLOT(B);
        ISSUE_SLOT(B); WAIT(36); CONSUME_SLOT(C);
    }
    ISSUE_SLOT(C); WAIT(36); CONSUME_SLOT(A);   // consume 192, issue 194
    ISSUE_SLOT(A); WAIT(36); CONSUME_SLOT(B);   // consume 193, issue 195
    WAIT(18); CONSUME_SLOT(C);                  // 194
    WAIT(0);  CONSUME_SLOT(A);                  // 195

    if (lane < 32) {
        ws_v[(side * S + s) * (B * D) + b0 * D + f] = v0;
        ws_v[(side * S + s) * (B * D) + b1 * D + f] = v1;
    }
}

// ---------------- fallback chain (round-1 style, used if ws too small) ----------------
__global__ __launch_bounds__(64) void chain_fb(
    const float* __restrict__ x, const float* __restrict__ A_first,
    const float* __restrict__ A_left, const float* __restrict__ A_right,
    const float* __restrict__ A_last, float* __restrict__ ws_v)
{
    const int blk = blockIdx.x, pair = blk & 7, b = blk >> 3;
    const int side = pair >> 2, s = pair & 3;
    const int lane = threadIdx.x, p = lane >> 5, j = lane & 31;
    const float* xb = x + b * (N * P);
    float v;
    if (side == 0) {
        v = fmaf(A_first[s*D*P + j*P + 0], xb[0], A_first[s*D*P + j*P + 1] * xb[1]);
        const float* Abase = A_left + (size_t)s * (NSTEP * D * P * D);
        for (int n = 1; n <= NSTEP; ++n) {
            const float* M = Abase + (n - 1) * (D * P * D) + p * D + j;
            const float x0 = xb[n*P], x1 = xb[n*P + 1];
            float t0 = 0.f, t1 = 0.f;
            #pragma unroll
            for (int i = 0; i < D; i += 2) {
                t0 = fmaf(bcast(v, i),     M[i * (P*D)],       t0);
                t1 = fmaf(bcast(v, i + 1), M[(i + 1) * (P*D)], t1);
            }
            const float t = t0 + t1, o = __shfl_xor(t, 32);
            v = (p == 0) ? fmaf(x0, t, x1 * o) : fmaf(x1, t, x0 * o);
        }
    } else {
        v = fmaf(A_last[s*D*P + j*P + 0], xb[(N-1)*P], A_last[s*D*P + j*P + 1] * xb[(N-1)*P + 1]);
        const float* Abase = A_right + (size_t)s * (NSTEP * D * P * D);
        for (int m = NSTEP - 1; m >= 0; --m) {
            const float4* R4 = (const float4*)(Abase + m * (D*P*D) + j * (P*D) + p * D);
            const float x0 = xb[(HALF+m)*P], x1 = xb[(HALF+m)*P + 1];
            float t0 = 0.f, t1 = 0.f;
            #pragma unroll
            for (int q = 0; q < 8; ++q) {
                const float4 rv = R4[q];
                t0 = fmaf(rv.x, bcast(v, 4*q+0), t0);
                t1 = fmaf(rv.y, bcast(v, 4*q+1), t1);
                t0 = fmaf(rv.z, bcast(v, 4*q+2), t0);
                t1 = fmaf(rv.w, bcast(v, 4*q+3), t1);
            }
            const float t = t0 + t1, o = __shfl_xor(t, 32);
            v = (p == 0) ? fmaf(x0, t, x1 * o) : fmaf(x1, t, x0 * o);
        }
    }
    if (p == 0) ws_v[(side*S + s)*(B*D) + b*D + j] = v;
}

// ---------------- fused label + product: 64 blocks (per b) x 64 threads ----------------
__global__ __launch_bounds__(64) void label_prod_kernel(
    const float* __restrict__ ws_v, const float* __restrict__ A_label,
    float* __restrict__ out)
{
    const int b = blockIdx.x;
    const int lane = threadIdx.x, h = lane >> 5, j = lane & 31;
    float pr0 = 1.f, pr1 = 1.f, pr2 = 1.f, pr3 = 1.f, pr4 = 1.f;

    #pragma unroll
    for (int s = 0; s < S; ++s) {
        const float vj = ws_v[(0 * S + s) * (B * D) + b * D + j];
        const float rj = ws_v[(1 * S + s) * (B * D) + b * D + j];
        #pragma unroll
        for (int q = 0; q < 5; ++q) {
            const int l = h * 5 + q;
            float w = 0.f;
            #pragma unroll
            for (int d = 0; d < D; ++d)
                w = fmaf(bcast(vj, d), A_label[((s * D + d) * L + l) * D + j], w);
            float c = w * rj;
            c += __shfl_xor(c, 1); c += __shfl_xor(c, 2); c += __shfl_xor(c, 4);
            c += __shfl_xor(c, 8); c += __shfl_xor(c, 16);
            if (q == 0) pr0 *= c; else if (q == 1) pr1 *= c;
            else if (q == 2) pr2 *= c; else if (q == 3) pr3 *= c; else pr4 *= c;
        }
    }
    if (j == 0) {
        out[b * L + h * 5 + 0] = pr0;
        out[b * L + h * 5 + 1] = pr1;
        out[b * L + h * 5 + 2] = pr2;
        out[b * L + h * 5 + 3] = pr3;
        out[b * L + h * 5 + 4] = pr4;
    }
}

extern "C" void kernel_launch(void* const* d_in, const int* in_sizes, int n_in,
                              void* d_out, int out_size, void* d_ws, size_t ws_size,
                              hipStream_t stream) {
    const float* x       = (const float*)d_in[0];
    const float* A_first = (const float*)d_in[1];
    const float* A_left  = (const float*)d_in[2];
    const float* A_label = (const float*)d_in[3];
    const float* A_right = (const float*)d_in[4];
    const float* A_last  = (const float*)d_in[5];
    float* out = (float*)d_out;

    float* ws_v = (float*)d_ws;                       // 16384 floats
    float* wtab = ws_v + 2 * S * B * D;               // 2*196*64*4 = 100352 floats
    float* Wbuf = wtab + 2 * NPAIR * 64 * 4;          // 8*196*4096 = 6422528 floats
    const size_t need = (size_t)(16384 + 100352 + 8 * NPAIR * SLICE) * 4;

    if (ws_size >= need) {
        pair_kernel<<<dim3(8, NPAIR), dim3(256), 0, stream>>>(A_left, A_right, x, Wbuf, wtab);
        chain_kernel<<<dim3(256), dim3(64), 0, stream>>>(x, A_first, A_last, Wbuf, wtab, ws_v);
    } else {
        chain_fb<<<dim3(2 * S * B), dim3(64), 0, stream>>>(x, A_first, A_left, A_right, A_last, ws_v);
    }
    label_prod_kernel<<<dim3(B), dim3(64), 0, stream>>>(ws_v, A_label, out);
}

// Round 6
// 119.075 us; speedup vs baseline: 1.0429x; 1.0429x over previous
//
#include <hip/hip_runtime.h>
#include <stdint.h>

#define S 4
#define B 64
#define D 32
#define N 784
#define P 2
#define L 10
#define HALF 392
#define NSTEP 391
#define NPAIR 196              // 195 real pairs + 1 leftover single site
#define SLICE 4096             // floats per pair slice: 4 combos * 32*32

typedef float f4 __attribute__((ext_vector_type(4)));

__device__ __forceinline__ float bcast(float v, int lane) {
    return __uint_as_float(__builtin_amdgcn_readlane(__float_as_uint(v), lane));
}

// ---------------- precompute: pair matrices + weight table ----------------
// W layout (per stream,t): float4-chunk index (bb*8+qq)*64 + lane, lane = c2*32+f,
// chunk holds content[c = c2+2*bb][f][e = 4*qq + r], r = component.
// left:  content[c][f][e] = P_c[e][f];  right: content[c][f][e] = Q_c[f][e].
// wtab layout: [(side*64 + b)*NPAIR + t] (float4) so chain prologue stages coalesced.
__global__ __launch_bounds__(256) void pair_kernel(
    const float* __restrict__ A_left, const float* __restrict__ A_right,
    const float* __restrict__ x,
    float* __restrict__ Wbuf, float* __restrict__ wtab)
{
    const int stream = blockIdx.x;      // 0..7 -> linear_id % 8 == stream (XCD pin)
    const int t      = blockIdx.y;      // 0..195
    const int side   = stream >> 2, s = stream & 3;
    __shared__ float sA[2048], sB[2048];
    const int tid = threadIdx.x;
    const bool leftover = (t == 195);

    const float* As = (side ? A_right : A_left) + (size_t)s * (NSTEP * 2048);
    int ia, ib;
    if (side == 0) { ia = 2 * t; ib = 2 * t + 1; }
    else           { ia = 389 - 2 * t; ib = 390 - 2 * t; }
    if (leftover)  { ia = side ? 0 : 390; ib = ia; }

    const float4* ga = (const float4*)(As + (size_t)ia * 2048);
    const float4* gb = (const float4*)(As + (size_t)ib * 2048);
    ((float4*)sA)[tid] = ga[tid]; ((float4*)sA)[tid + 256] = ga[tid + 256];
    ((float4*)sB)[tid] = gb[tid]; ((float4*)sB)[tid + 256] = gb[tid + 256];
    __syncthreads();

    const int c = tid >> 6, rest = tid & 63, ff = rest >> 1, eh = rest & 1;
    const int a = c & 1, bb = c >> 1;
    float out[16];

    if (!leftover) {
        if (side == 0) {
            float col[32];
            #pragma unroll
            for (int k = 0; k < 32; ++k) col[k] = sB[k * 64 + bb * 32 + ff];
            #pragma unroll
            for (int e0 = 0; e0 < 16; ++e0) {
                const int e = eh * 16 + e0; float acc = 0.f;
                #pragma unroll
                for (int k = 0; k < 32; ++k)
                    acc = fmaf(sA[e * 64 + a * 32 + k], col[k], acc);
                out[e0] = acc;
            }
        } else {
            float row[32];
            #pragma unroll
            for (int k = 0; k < 32; ++k) row[k] = sA[ff * 64 + a * 32 + k];
            #pragma unroll
            for (int e0 = 0; e0 < 16; ++e0) {
                const int e = eh * 16 + e0; float acc = 0.f;
                #pragma unroll
                for (int k = 0; k < 32; ++k)
                    acc = fmaf(row[k], sB[k * 64 + bb * 32 + e], acc);
                out[e0] = acc;
            }
        }
    } else {
        #pragma unroll
        for (int e0 = 0; e0 < 16; ++e0) {
            const int e = eh * 16 + e0;
            out[e0] = (side == 0) ? sA[e * 64 + a * 32 + ff]
                                  : sA[ff * 64 + a * 32 + e];
        }
    }

    float* Wt = Wbuf + ((size_t)stream * NPAIR + t) * SLICE;
    #pragma unroll
    for (int q0 = 0; q0 < 4; ++q0) {
        const int qq = eh * 4 + q0;
        float4 val = make_float4(out[q0 * 4 + 0], out[q0 * 4 + 1],
                                 out[q0 * 4 + 2], out[q0 * 4 + 3]);
        ((float4*)Wt)[(bb * 8 + qq) * 64 + a * 32 + ff] = val;
    }

    // fused weight table: w[c=a+2b] = xa[a]*xb[b] for (side = stream, t, b = tid)
    if (stream < 2 && tid < 64) {
        const int sd = stream;
        const float2* x2 = (const float2*)x;
        float2 xa, xb;
        if (!leftover) {
            int na, nb;
            if (sd == 0) { na = 2 * t + 1; nb = 2 * t + 2; }
            else         { int ma = 389 - 2 * t; na = HALF + ma; nb = na + 1; }
            xa = x2[(size_t)tid * N + na];
            xb = x2[(size_t)tid * N + nb];
        } else {
            xa = x2[(size_t)tid * N + (sd ? HALF : 391)];
            xb = make_float2(1.f, 0.f);
        }
        float4 w = make_float4(xa.x * xb.x, xa.y * xb.x, xa.x * xb.y, xa.y * xb.y);
        ((float4*)wtab)[((size_t)sd * 64 + tid) * NPAIR + t] = w;
    }
}

// ---------------- chain kernel: 2-slot register ring, no spill ----------------
// saddr-form loads: SGPR64 base per 4KB group, one 32-bit voffset, imm chunk offs.
#define GLOADX4(dst, voff, base, off) \
    asm volatile("global_load_dwordx4 %0, %1, %2 offset:" #off \
                 : "=v"(dst) : "v"(voff), "s"(base))

#define ISSUE_SLOT(SL) do { \
    GLOADX4(SL##0,  voff, base0, 0); GLOADX4(SL##1,  voff, base0, 1024); \
    GLOADX4(SL##2,  voff, base0, 2048); GLOADX4(SL##3,  voff, base0, 3072); \
    GLOADX4(SL##4,  voff, base1, 0); GLOADX4(SL##5,  voff, base1, 1024); \
    GLOADX4(SL##6,  voff, base1, 2048); GLOADX4(SL##7,  voff, base1, 3072); \
    GLOADX4(SL##8,  voff, base2, 0); GLOADX4(SL##9,  voff, base2, 1024); \
    GLOADX4(SL##10, voff, base2, 2048); GLOADX4(SL##11, voff, base2, 3072); \
    GLOADX4(SL##12, voff, base3, 0); GLOADX4(SL##13, voff, base3, 1024); \
    GLOADX4(SL##14, voff, base3, 2048); GLOADX4(SL##15, voff, base3, 3072); \
    voff += 16384; \
} while (0)

#define WAIT(n) do { \
    asm volatile("s_waitcnt vmcnt(" #n ")"); \
    __builtin_amdgcn_sched_barrier(0); \
} while (0)

// One e-quad element: RL = combo c2 chunk, RH = combo c2+2 chunk; readlane CSE.
#define FMAD2_1(RL_, RH_, aL0, aH0, aL1, aH1, E) do { \
    const float s_ = bcast(v0, E), t_ = bcast(v1, E); \
    aL0 = fmaf(RL_, s_, aL0); aH0 = fmaf(RH_, s_, aH0); \
    aL1 = fmaf(RL_, t_, aL1); aH1 = fmaf(RH_, t_, aH1); \
} while (0)

#define FMAD2(RqL, RqH, aL0, aH0, aL1, aH1, eb) \
    FMAD2_1(RqL.x, RqH.x, aL0, aH0, aL1, aH1, eb + 0); \
    FMAD2_1(RqL.y, RqH.y, aL0, aH0, aL1, aH1, eb + 1); \
    FMAD2_1(RqL.z, RqH.z, aL0, aH0, aL1, aH1, eb + 2); \
    FMAD2_1(RqL.w, RqH.w, aL0, aH0, aL1, aH1, eb + 3);

#define CONSUME_SLOT(SL, W0, W1) do { \
    float q00 = 0.f, q01 = 0.f, q02 = 0.f, q03 = 0.f; \
    float q10 = 0.f, q11 = 0.f, q12 = 0.f, q13 = 0.f; \
    FMAD2(SL##0, SL##8,  q00, q02, q10, q12, 0)  \
    FMAD2(SL##1, SL##9,  q00, q02, q10, q12, 4)  \
    FMAD2(SL##2, SL##10, q00, q02, q10, q12, 8)  \
    FMAD2(SL##3, SL##11, q00, q02, q10, q12, 12) \
    FMAD2(SL##4, SL##12, q01, q03, q11, q13, 16) \
    FMAD2(SL##5, SL##13, q01, q03, q11, q13, 20) \
    FMAD2(SL##6, SL##14, q01, q03, q11, q13, 24) \
    FMAD2(SL##7, SL##15, q01, q03, q11, q13, 28) \
    const float wl0 = c2 ? W0.y : W0.x, wh0 = c2 ? W0.w : W0.z; \
    const float wl1 = c2 ? W1.y : W1.x, wh1 = c2 ? W1.w : W1.z; \
    const float part0 = fmaf(wl0, q00 + q01, wh0 * (q02 + q03)); \
    const float part1 = fmaf(wl1, q10 + q11, wh1 * (q12 + q13)); \
    v0 = part0 + __shfl_xor(part0, 32); \
    v1 = part1 + __shfl_xor(part1, 32); \
} while (0)

// 256 blocks x 64 threads: 1 wave = 2 chains (b0,b1) of one stream.
// blk&7 = stream (XCD-pinned). lane = (c2, f). Weights via LDS (lgkmcnt),
// slice loads via exact counted vmcnt: 16 per slot, 2 slots in flight.
__global__ __launch_bounds__(64, 1) void chain_kernel(
    const float* __restrict__ x,
    const float* __restrict__ A_first, const float* __restrict__ A_last,
    const float* __restrict__ Wbuf, const float* __restrict__ wtab,
    float* __restrict__ ws_v)
{
    __shared__ float4 lw[2 * NPAIR];   // [t][chain] interleaved: lw[2t], lw[2t+1]

    const int lane = threadIdx.x, c2 = lane >> 5, f = lane & 31;
    const int blk = blockIdx.x, stream = blk & 7;
    const int side = stream >> 2, s = stream & 3;
    const int bp = blk >> 3;              // 0..31
    const int b0 = 2 * bp, b1 = 2 * bp + 1;

    // stage weights to LDS (coalesced reads from wtab[side][b][t])
    const float4* wt4 = (const float4*)wtab;
    for (int i = lane; i < NPAIR; i += 64) {
        lw[2 * i]     = wt4[((size_t)side * 64 + b0) * NPAIR + i];
        lw[2 * i + 1] = wt4[((size_t)side * 64 + b1) * NPAIR + i];
    }

    const float2* x2 = (const float2*)x;
    const int site0 = side ? (N - 1) : 0;
    const float2 af  = ((const float2*)(side ? A_last : A_first))[s * D + f];
    const float2 xx0 = x2[(size_t)b0 * N + site0];
    const float2 xx1 = x2[(size_t)b1 * N + site0];
    float v0 = fmaf(af.x, xx0.x, af.y * xx0.y);
    float v1 = fmaf(af.x, xx1.x, af.y * xx1.y);

    const uint64_t wbase = (uint64_t)((const char*)Wbuf
                         + (size_t)stream * (NPAIR * SLICE) * 4);
    const uint64_t base0 = wbase, base1 = wbase + 4096;
    const uint64_t base2 = wbase + 8192, base3 = wbase + 12288;
    uint32_t voff = (uint32_t)lane * 16;

    f4 A0,A1,A2,A3,A4,A5,A6,A7,A8,A9,A10,A11,A12,A13,A14,A15;
    f4 B0,B1,B2,B3,B4,B5,B6,B7,B8,B9,B10,B11,B12,B13,B14,B15;

    ISSUE_SLOT(A);   // t = 0
    ISSUE_SLOT(B);   // t = 1
    float4 wA0 = lw[0], wA1 = lw[1];      // weights for t=0
    float4 wB0 = lw[2], wB1 = lw[3];      // weights for t=1

    for (int k = 0; k < 97; ++k) {        // consumes t = 0..193, issues t = 2..195
        WAIT(16); CONSUME_SLOT(A, wA0, wA1);        // t = 2k
        ISSUE_SLOT(A);                              // t = 2k+2
        wA0 = lw[2 * (2 * k + 2)]; wA1 = lw[2 * (2 * k + 2) + 1];
        WAIT(16); CONSUME_SLOT(B, wB0, wB1);        // t = 2k+1
        ISSUE_SLOT(B);                              // t = 2k+3
        wB0 = lw[2 * (2 * k + 3)]; wB1 = lw[2 * (2 * k + 3) + 1];
    }
    WAIT(16); CONSUME_SLOT(A, wA0, wA1);            // t = 194
    WAIT(0);  CONSUME_SLOT(B, wB0, wB1);            // t = 195

    if (lane < 32) {
        ws_v[(side * S + s) * (B * D) + b0 * D + f] = v0;
        ws_v[(side * S + s) * (B * D) + b1 * D + f] = v1;
    }
}

// ---------------- fallback chain (round-1 style, used if ws too small) ----------------
__global__ __launch_bounds__(64) void chain_fb(
    const float* __restrict__ x, const float* __restrict__ A_first,
    const float* __restrict__ A_left, const float* __restrict__ A_right,
    const float* __restrict__ A_last, float* __restrict__ ws_v)
{
    const int blk = blockIdx.x, pair = blk & 7, b = blk >> 3;
    const int side = pair >> 2, s = pair & 3;
    const int lane = threadIdx.x, p = lane >> 5, j = lane & 31;
    const float* xb = x + b * (N * P);
    float v;
    if (side == 0) {
        v = fmaf(A_first[s*D*P + j*P + 0], xb[0], A_first[s*D*P + j*P + 1] * xb[1]);
        const float* Abase = A_left + (size_t)s * (NSTEP * D * P * D);
        for (int n = 1; n <= NSTEP; ++n) {
            const float* M = Abase + (n - 1) * (D * P * D) + p * D + j;
            const float x0 = xb[n*P], x1 = xb[n*P + 1];
            float t0 = 0.f, t1 = 0.f;
            #pragma unroll
            for (int i = 0; i < D; i += 2) {
                t0 = fmaf(bcast(v, i),     M[i * (P*D)],       t0);
                t1 = fmaf(bcast(v, i + 1), M[(i + 1) * (P*D)], t1);
            }
            const float t = t0 + t1, o = __shfl_xor(t, 32);
            v = (p == 0) ? fmaf(x0, t, x1 * o) : fmaf(x1, t, x0 * o);
        }
    } else {
        v = fmaf(A_last[s*D*P + j*P + 0], xb[(N-1)*P], A_last[s*D*P + j*P + 1] * xb[(N-1)*P + 1]);
        const float* Abase = A_right + (size_t)s * (NSTEP * D * P * D);
        for (int m = NSTEP - 1; m >= 0; --m) {
            const float4* R4 = (const float4*)(Abase + m * (D*P*D) + j * (P*D) + p * D);
            const float x0 = xb[(HALF+m)*P], x1 = xb[(HALF+m)*P + 1];
            float t0 = 0.f, t1 = 0.f;
            #pragma unroll
            for (int q = 0; q < 8; ++q) {
                const float4 rv = R4[q];
                t0 = fmaf(rv.x, bcast(v, 4*q+0), t0);
                t1 = fmaf(rv.y, bcast(v, 4*q+1), t1);
                t0 = fmaf(rv.z, bcast(v, 4*q+2), t0);
                t1 = fmaf(rv.w, bcast(v, 4*q+3), t1);
            }
            const float t = t0 + t1, o = __shfl_xor(t, 32);
            v = (p == 0) ? fmaf(x0, t, x1 * o) : fmaf(x1, t, x0 * o);
        }
    }
    if (p == 0) ws_v[(side*S + s)*(B*D) + b*D + j] = v;
}

// ---------------- fused label + product: 64 blocks (per b) x 64 threads ----------------
__global__ __launch_bounds__(64) void label_prod_kernel(
    const float* __restrict__ ws_v, const float* __restrict__ A_label,
    float* __restrict__ out)
{
    const int b = blockIdx.x;
    const int lane = threadIdx.x, h = lane >> 5, j = lane & 31;
    float pr0 = 1.f, pr1 = 1.f, pr2 = 1.f, pr3 = 1.f, pr4 = 1.f;

    #pragma unroll
    for (int s = 0; s < S; ++s) {
        const float vj = ws_v[(0 * S + s) * (B * D) + b * D + j];
        const float rj = ws_v[(1 * S + s) * (B * D) + b * D + j];
        #pragma unroll
        for (int q = 0; q < 5; ++q) {
            const int l = h * 5 + q;
            float w = 0.f;
            #pragma unroll
            for (int d = 0; d < D; ++d)
                w = fmaf(bcast(vj, d), A_label[((s * D + d) * L + l) * D + j], w);
            float c = w * rj;
            c += __shfl_xor(c, 1); c += __shfl_xor(c, 2); c += __shfl_xor(c, 4);
            c += __shfl_xor(c, 8); c += __shfl_xor(c, 16);
            if (q == 0) pr0 *= c; else if (q == 1) pr1 *= c;
            else if (q == 2) pr2 *= c; else if (q == 3) pr3 *= c; else pr4 *= c;
        }
    }
    if (j == 0) {
        out[b * L + h * 5 + 0] = pr0;
        out[b * L + h * 5 + 1] = pr1;
        out[b * L + h * 5 + 2] = pr2;
        out[b * L + h * 5 + 3] = pr3;
        out[b * L + h * 5 + 4] = pr4;
    }
}

extern "C" void kernel_launch(void* const* d_in, const int* in_sizes, int n_in,
                              void* d_out, int out_size, void* d_ws, size_t ws_size,
                              hipStream_t stream) {
    const float* x       = (const float*)d_in[0];
    const float* A_first = (const float*)d_in[1];
    const float* A_left  = (const float*)d_in[2];
    const float* A_label = (const float*)d_in[3];
    const float* A_right = (const float*)d_in[4];
    const float* A_last  = (const float*)d_in[5];
    float* out = (float*)d_out;

    float* ws_v = (float*)d_ws;                       // 16384 floats
    float* wtab = ws_v + 2 * S * B * D;               // 2*64*196*4 = 100352 floats
    float* Wbuf = wtab + 2 * 64 * NPAIR * 4;          // 8*196*4096 = 6422528 floats
    const size_t need = (size_t)(16384 + 100352 + 8 * NPAIR * SLICE) * 4;

    if (ws_size >= need) {
        pair_kernel<<<dim3(8, NPAIR), dim3(256), 0, stream>>>(A_left, A_right, x, Wbuf, wtab);
        chain_kernel<<<dim3(256), dim3(64), 0, stream>>>(x, A_first, A_last, Wbuf, wtab, ws_v);
    } else {
        chain_fb<<<dim3(2 * S * B), dim3(64), 0, stream>>>(x, A_first, A_left, A_right, A_last, ws_v);
    }
    label_prod_kernel<<<dim3(B), dim3(64), 0, stream>>>(ws_v, A_label, out);
}